// Round 2
// baseline (547.725 us; speedup 1.0000x reference)
//
#include <hip/hip_runtime.h>
#include <hip/hip_bf16.h>

#define M_DIM 8192
#define N_DIM 4096
#define K_DIM 4096

typedef _Float16 f16;
typedef _Float16 f16x8 __attribute__((ext_vector_type(8)));
typedef float f32x4 __attribute__((ext_vector_type(4)));

// async global->LDS, 16B per lane. LDS dest is wave-uniform base; HW stores lane i at base + i*16.
__device__ __forceinline__ void lds_async16(void* lds, const void* g) {
    __builtin_amdgcn_global_load_lds(
        (const __attribute__((address_space(1))) void*)(void*)g,
        (__attribute__((address_space(3))) void*)lds, 16, 0, 0);
}

// ---- prepass: fp32 x -> f16 (8 floats / thread) ----
__global__ __launch_bounds__(256) void cvt_x_kernel(const float* __restrict__ x, f16* __restrict__ xh) {
    size_t idx  = (size_t)blockIdx.x * 256 + threadIdx.x;
    size_t base = idx * 8;
    const float4* xp = (const float4*)(x + base);
    float4 v0 = xp[0], v1 = xp[1];
    f16x8 h;
    h[0] = (f16)v0.x; h[1] = (f16)v0.y; h[2] = (f16)v0.z; h[3] = (f16)v0.w;
    h[4] = (f16)v1.x; h[5] = (f16)v1.y; h[6] = (f16)v1.z; h[7] = (f16)v1.w;
    *(f16x8*)(xh + base) = h;
}

// ---- prepass: packed int4 (one byte per int32, hi nibble first) -> f16 Q in [-8,7] ----
__global__ __launch_bounds__(256) void cvt_w_kernel(const int* __restrict__ pw, f16* __restrict__ wh) {
    size_t idx = (size_t)blockIdx.x * 256 + threadIdx.x;  // 4 ints / thread -> 8 halves
    int4 v = ((const int4*)pw)[idx];
    f16x8 h;
    int a;
    a = v.x; h[0] = (f16)(((a >> 4) & 15) - 8); h[1] = (f16)((a & 15) - 8);
    a = v.y; h[2] = (f16)(((a >> 4) & 15) - 8); h[3] = (f16)((a & 15) - 8);
    a = v.z; h[4] = (f16)(((a >> 4) & 15) - 8); h[5] = (f16)((a & 15) - 8);
    a = v.w; h[6] = (f16)(((a >> 4) & 15) - 8); h[7] = (f16)((a & 15) - 8);
    *(f16x8*)(wh + idx * 8) = h;
}

// ---- main GEMM: C[M,N] = sw * (A[M,K] @ B[N,K]^T) + bias[N], f16 MFMA, m97 structure ----
// LDS chunk layout (1KB = 16 rows x 32 halves), XOR-swizzled to kill ds_read_b128
// bank conflicts: slot s holds (row = s>>2, kchunk = (s&3) ^ ((s>>3)&3)).
// A 16-lane read phase then covers all 8 bank-groups exactly 2x (2-way = free, m136).
__global__ __launch_bounds__(256) void gemm_f16(const f16* __restrict__ A, const f16* __restrict__ B,
                                                const int* __restrict__ pb,
                                                const float* __restrict__ psw, const float* __restrict__ psb,
                                                float* __restrict__ out) {
    __shared__ f16 As[128 * 32];   // 8 KB, 8 chunks of 1KB
    __shared__ f16 Bs[128 * 32];   // 8 KB

    const int tid  = threadIdx.x;
    const int wave = tid >> 6;
    const int lane = tid & 63;
    const int wm   = wave >> 1;          // wave tile: 2x2 waves of 64x64
    const int wn   = wave & 1;
    const int quad = lane >> 4;
    const int l16  = lane & 15;

    const int mbase = blockIdx.y * 128;
    const int nbase = blockIdx.x * 128;

    // staging: lane i fills slot i of its chunk -> load row i>>2, kchunk (i&3)^((i>>3)&3)
    const int srow = lane >> 2;                                // 0..15 within chunk
    const int scol = ((lane & 3) ^ ((lane >> 3) & 3)) * 8;     // swizzled kchunk, in halves

    const f16* aP0 = A + (size_t)(mbase + wave * 32 + srow) * K_DIM + scol;
    const f16* aP1 = aP0 + (size_t)16 * K_DIM;
    const f16* bP0 = B + (size_t)(nbase + wave * 32 + srow) * K_DIM + scol;
    const f16* bP1 = bP0 + (size_t)16 * K_DIM;

    f16* aD0 = As + (wave * 2 + 0) * 512;
    f16* aD1 = As + (wave * 2 + 1) * 512;
    f16* bD0 = Bs + (wave * 2 + 0) * 512;
    f16* bD1 = Bs + (wave * 2 + 1) * 512;

    f32x4 acc[4][4] = {};

    // fragment read: lane (quad,l16) reads slot l16*4 + (quad ^ ((l16>>1)&3)) of its chunk
    const int aslot = (l16 * 4 + (quad ^ ((l16 >> 1) & 3))) * 8;   // in halves

    for (int k0 = 0; k0 < K_DIM; k0 += 32) {
        lds_async16(aD0, aP0);
        lds_async16(aD1, aP1);
        lds_async16(bD0, bP0);
        lds_async16(bD1, bP1);
        aP0 += 32; aP1 += 32; bP0 += 32; bP1 += 32;
        __syncthreads();   // drains vmcnt -> staged data visible

        f16x8 af[4], bf[4];
#pragma unroll
        for (int mt = 0; mt < 4; mt++)
            af[mt] = *(const f16x8*)&As[(wm * 4 + mt) * 512 + aslot];
#pragma unroll
        for (int nt = 0; nt < 4; nt++)
            bf[nt] = *(const f16x8*)&Bs[(wn * 4 + nt) * 512 + aslot];

#pragma unroll
        for (int mt = 0; mt < 4; mt++)
#pragma unroll
            for (int nt = 0; nt < 4; nt++)
                acc[mt][nt] = __builtin_amdgcn_mfma_f32_16x16x32_f16(af[mt], bf[nt], acc[mt][nt], 0, 0, 0);

        __syncthreads();   // all waves done reading before next overwrite
    }

    const float sw = *psw;
    const float sb = *psb;

#pragma unroll
    for (int nt = 0; nt < 4; nt++) {
        const int gcol = nbase + wn * 64 + nt * 16 + l16;
        const int p    = pb[gcol >> 1];
        const int nib  = (gcol & 1) ? (p & 15) : ((p >> 4) & 15);
        const float bias = sb * (float)(nib - 8);
#pragma unroll
        for (int mt = 0; mt < 4; mt++) {
            const int grow = mbase + wm * 64 + mt * 16 + quad * 4;
            float* o = out + (size_t)grow * N_DIM + gcol;
#pragma unroll
            for (int r = 0; r < 4; r++)
                o[(size_t)r * N_DIM] = sw * acc[mt][nt][r] + bias;
        }
    }
}

// ---- correct-but-slow fallback if workspace is too small for the f16 copies ----
__global__ __launch_bounds__(256) void gemm_fallback(const float* __restrict__ x, const int* __restrict__ pw,
                                                     const int* __restrict__ pb,
                                                     const float* __restrict__ psw, const float* __restrict__ psb,
                                                     float* __restrict__ out) {
    __shared__ float As[16][17];
    __shared__ float Bs[16][17];
    const int tx = threadIdx.x & 15, ty = threadIdx.x >> 4;
    const int row = blockIdx.y * 16 + ty;   // m
    const int col = blockIdx.x * 16 + tx;   // n
    float acc = 0.f;
    for (int k0 = 0; k0 < K_DIM; k0 += 16) {
        As[ty][tx] = x[(size_t)row * K_DIM + k0 + tx];
        const int nrow = blockIdx.x * 16 + ty;
        const int k = k0 + tx;
        const int p = pw[((size_t)nrow * K_DIM + k) >> 1];
        const int nib = (k & 1) ? (p & 15) : ((p >> 4) & 15);
        Bs[ty][tx] = (float)(nib - 8);
        __syncthreads();
#pragma unroll
        for (int kk = 0; kk < 16; kk++)
            acc += As[ty][kk] * Bs[tx][kk];
        __syncthreads();
    }
    const float sw = *psw, sb = *psb;
    const int p = pb[col >> 1];
    const int nib = (col & 1) ? (p & 15) : ((p >> 4) & 15);
    out[(size_t)row * N_DIM + col] = sw * acc + sb * (float)(nib - 8);
}

extern "C" void kernel_launch(void* const* d_in, const int* in_sizes, int n_in,
                              void* d_out, int out_size, void* d_ws, size_t ws_size,
                              hipStream_t stream) {
    (void)in_sizes; (void)n_in; (void)out_size;
    const float* x   = (const float*)d_in[0];
    const int*   pw  = (const int*)d_in[1];
    const int*   pb  = (const int*)d_in[2];
    const float* psw = (const float*)d_in[3];
    const float* psb = (const float*)d_in[4];
    float* out = (float*)d_out;

    const size_t xh_bytes = (size_t)M_DIM * K_DIM * sizeof(f16);   // 67.1 MB
    const size_t wh_bytes = (size_t)N_DIM * K_DIM * sizeof(f16);   // 33.6 MB

    if (ws_size >= xh_bytes + wh_bytes) {
        f16* xh = (f16*)d_ws;
        f16* wh = (f16*)((char*)d_ws + xh_bytes);
        cvt_x_kernel<<<(M_DIM * (size_t)K_DIM) / 8 / 256, 256, 0, stream>>>(x, xh);
        cvt_w_kernel<<<((size_t)N_DIM * K_DIM / 2) / 4 / 256, 256, 0, stream>>>(pw, wh);
        gemm_f16<<<dim3(N_DIM / 128, M_DIM / 128), 256, 0, stream>>>(xh, wh, pb, psw, psb, out);
    } else {
        gemm_fallback<<<dim3(N_DIM / 16, M_DIM / 16), 256, 0, stream>>>(x, pw, pb, psw, psb, out);
    }
}

// Round 3
// 506.682 us; speedup vs baseline: 1.0810x; 1.0810x over previous
//
#include <hip/hip_runtime.h>
#include <hip/hip_bf16.h>

#define M_DIM 8192
#define N_DIM 4096
#define K_DIM 4096

typedef _Float16 f16;
typedef _Float16 f16x8 __attribute__((ext_vector_type(8)));
typedef float f32x16 __attribute__((ext_vector_type(16)));

// async global->LDS, 16B per lane. LDS dest is wave-uniform base; HW stores lane i at base + i*16.
__device__ __forceinline__ void lds_async16(void* lds, const void* g) {
    __builtin_amdgcn_global_load_lds(
        (const __attribute__((address_space(1))) void*)(void*)g,
        (__attribute__((address_space(3))) void*)lds, 16, 0, 0);
}

// ---- prepass: fp32 x -> f16 (8 floats / thread) ----
__global__ __launch_bounds__(256) void cvt_x_kernel(const float* __restrict__ x, f16* __restrict__ xh) {
    size_t idx  = (size_t)blockIdx.x * 256 + threadIdx.x;
    size_t base = idx * 8;
    const float4* xp = (const float4*)(x + base);
    float4 v0 = xp[0], v1 = xp[1];
    f16x8 h;
    h[0] = (f16)v0.x; h[1] = (f16)v0.y; h[2] = (f16)v0.z; h[3] = (f16)v0.w;
    h[4] = (f16)v1.x; h[5] = (f16)v1.y; h[6] = (f16)v1.z; h[7] = (f16)v1.w;
    *(f16x8*)(xh + base) = h;
}

// ---- prepass: packed int4 (one byte per int32, hi nibble first) -> f16 Q in [-8,7] ----
__global__ __launch_bounds__(256) void cvt_w_kernel(const int* __restrict__ pw, f16* __restrict__ wh) {
    size_t idx = (size_t)blockIdx.x * 256 + threadIdx.x;  // 4 ints / thread -> 8 halves
    int4 v = ((const int4*)pw)[idx];
    f16x8 h;
    int a;
    a = v.x; h[0] = (f16)(((a >> 4) & 15) - 8); h[1] = (f16)((a & 15) - 8);
    a = v.y; h[2] = (f16)(((a >> 4) & 15) - 8); h[3] = (f16)((a & 15) - 8);
    a = v.z; h[4] = (f16)(((a >> 4) & 15) - 8); h[5] = (f16)((a & 15) - 8);
    a = v.w; h[6] = (f16)(((a >> 4) & 15) - 8); h[7] = (f16)((a & 15) - 8);
    *(f16x8*)(wh + idx * 8) = h;
}

// ---- main GEMM: C[M,N] = sw * (A[M,K] @ B[N,K]^T) + bias[N] ----
// 128x128 block tile, 4 waves (2x2 of 64x64), BK=64, v_mfma_f32_32x32x16_f16.
// LDS: per operand 128 rows x 64 halves = 16 KB, as 16 chunks of 1 KB.
// Chunk = 8 rows x 8 16B-kchunks; XOR swizzle slot(rr,kc) = rr*8 + (kc^rr)
// -> every 16-lane ds_read_b128 phase covers all 8 bank groups 2x (free, m136).
__global__ __launch_bounds__(256) void gemm_f16(const f16* __restrict__ A, const f16* __restrict__ B,
                                                const int* __restrict__ pb,
                                                const float* __restrict__ psw, const float* __restrict__ psb,
                                                float* __restrict__ out) {
    __shared__ f16 As[128 * 64];   // 16 KB
    __shared__ f16 Bs[128 * 64];   // 16 KB

    const int tid  = threadIdx.x;
    const int wave = tid >> 6;
    const int lane = tid & 63;
    const int wm   = wave >> 1;          // 2x2 waves of 64x64
    const int wn   = wave & 1;
    const int half = lane >> 5;          // 0/1
    const int l32  = lane & 31;

    const int mbase = blockIdx.y * 128;
    const int nbase = blockIdx.x * 128;

    // staging: lane i fills slot i of a chunk -> row i>>3 (in-chunk), kchunk (i&7)^(i>>3)
    const int srow = lane >> 3;                    // 0..7
    const int scol = ((lane & 7) ^ srow) * 8;      // halves

    // wave w stages A rows [w*32, w*32+32) (chunks 4w..4w+3) and same for B
    const f16* aP[4]; const f16* bP[4];
    f16* aD[4]; f16* bD[4];
#pragma unroll
    for (int j = 0; j < 4; j++) {
        aP[j] = A + (size_t)(mbase + wave * 32 + j * 8 + srow) * K_DIM + scol;
        bP[j] = B + (size_t)(nbase + wave * 32 + j * 8 + srow) * K_DIM + scol;
        aD[j] = As + (wave * 4 + j) * 512;
        bD[j] = Bs + (wave * 4 + j) * 512;
    }

    f32x16 acc[2][2] = {};

    // fragment read bases: for m-subtile mt, row r = wm*64 + mt*32 + l32
    // addr(halves) = (r>>3)*512 + (r&7)*64 + ((kc ^ (r&7)))*8, kc = kk/8 + half
    int abase[2], bbase[2], arr[2], brr[2];
#pragma unroll
    for (int t = 0; t < 2; t++) {
        int ra = wm * 64 + t * 32 + l32;
        int rb = wn * 64 + t * 32 + l32;
        abase[t] = (ra >> 3) * 512 + (ra & 7) * 64;
        arr[t]   = ra & 7;
        bbase[t] = (rb >> 3) * 512 + (rb & 7) * 64;
        brr[t]   = rb & 7;
    }

    for (int k0 = 0; k0 < K_DIM; k0 += 64) {
#pragma unroll
        for (int j = 0; j < 4; j++) {
            lds_async16(aD[j], aP[j]);
            lds_async16(bD[j], bP[j]);
            aP[j] += 64; bP[j] += 64;
        }
        __syncthreads();   // drains vmcnt -> staged data visible

#pragma unroll
        for (int kk = 0; kk < 64; kk += 16) {
            const int kc = (kk >> 3) + half;
            f16x8 af[2], bf[2];
#pragma unroll
            for (int t = 0; t < 2; t++) {
                af[t] = *(const f16x8*)&As[abase[t] + (kc ^ arr[t]) * 8];
                bf[t] = *(const f16x8*)&Bs[bbase[t] + (kc ^ brr[t]) * 8];
            }
#pragma unroll
            for (int mt = 0; mt < 2; mt++)
#pragma unroll
                for (int nt = 0; nt < 2; nt++)
                    acc[mt][nt] = __builtin_amdgcn_mfma_f32_32x32x16_f16(af[mt], bf[nt], acc[mt][nt], 0, 0, 0);
        }

        __syncthreads();   // all waves done reading before next overwrite
    }

    const float sw = *psw;
    const float sb = *psb;

    // C/D layout (m74/m101): col = lane&31, row = (reg&3) + 8*(reg>>2) + 4*(lane>>5)
#pragma unroll
    for (int nt = 0; nt < 2; nt++) {
        const int gcol = nbase + wn * 64 + nt * 32 + l32;
        const int p    = pb[gcol >> 1];
        const int nib  = (gcol & 1) ? (p & 15) : ((p >> 4) & 15);
        const float bias = sb * (float)(nib - 8);
#pragma unroll
        for (int mt = 0; mt < 2; mt++) {
            const int rbase = mbase + wm * 64 + mt * 32 + half * 4;
#pragma unroll
            for (int g = 0; g < 4; g++) {
                float* o = out + (size_t)(rbase + g * 8) * N_DIM + gcol;
#pragma unroll
                for (int r = 0; r < 4; r++)
                    o[(size_t)r * N_DIM] = sw * acc[mt][nt][g * 4 + r] + bias;
            }
        }
    }
}

// ---- correct-but-slow fallback if workspace is too small for the f16 copies ----
__global__ __launch_bounds__(256) void gemm_fallback(const float* __restrict__ x, const int* __restrict__ pw,
                                                     const int* __restrict__ pb,
                                                     const float* __restrict__ psw, const float* __restrict__ psb,
                                                     float* __restrict__ out) {
    __shared__ float As[16][17];
    __shared__ float Bs[16][17];
    const int tx = threadIdx.x & 15, ty = threadIdx.x >> 4;
    const int row = blockIdx.y * 16 + ty;   // m
    const int col = blockIdx.x * 16 + tx;   // n
    float acc = 0.f;
    for (int k0 = 0; k0 < K_DIM; k0 += 16) {
        As[ty][tx] = x[(size_t)row * K_DIM + k0 + tx];
        const int nrow = blockIdx.x * 16 + ty;
        const int k = k0 + tx;
        const int p = pw[((size_t)nrow * K_DIM + k) >> 1];
        const int nib = (k & 1) ? (p & 15) : ((p >> 4) & 15);
        Bs[ty][tx] = (float)(nib - 8);
        __syncthreads();
#pragma unroll
        for (int kk = 0; kk < 16; kk++)
            acc += As[ty][kk] * Bs[tx][kk];
        __syncthreads();
    }
    const float sw = *psw, sb = *psb;
    const int p = pb[col >> 1];
    const int nib = (col & 1) ? (p & 15) : ((p >> 4) & 15);
    out[(size_t)row * N_DIM + col] = sw * acc + sb * (float)(nib - 8);
}

extern "C" void kernel_launch(void* const* d_in, const int* in_sizes, int n_in,
                              void* d_out, int out_size, void* d_ws, size_t ws_size,
                              hipStream_t stream) {
    (void)in_sizes; (void)n_in; (void)out_size;
    const float* x   = (const float*)d_in[0];
    const int*   pw  = (const int*)d_in[1];
    const int*   pb  = (const int*)d_in[2];
    const float* psw = (const float*)d_in[3];
    const float* psb = (const float*)d_in[4];
    float* out = (float*)d_out;

    const size_t xh_bytes = (size_t)M_DIM * K_DIM * sizeof(f16);   // 67.1 MB
    const size_t wh_bytes = (size_t)N_DIM * K_DIM * sizeof(f16);   // 33.6 MB

    if (ws_size >= xh_bytes + wh_bytes) {
        f16* xh = (f16*)d_ws;
        f16* wh = (f16*)((char*)d_ws + xh_bytes);
        cvt_x_kernel<<<(M_DIM * (size_t)K_DIM) / 8 / 256, 256, 0, stream>>>(x, xh);
        cvt_w_kernel<<<((size_t)N_DIM * K_DIM / 2) / 4 / 256, 256, 0, stream>>>(pw, wh);
        gemm_f16<<<dim3(N_DIM / 128, M_DIM / 128), 256, 0, stream>>>(xh, wh, pb, psw, psb, out);
    } else {
        gemm_fallback<<<dim3(N_DIM / 16, M_DIM / 16), 256, 0, stream>>>(x, pw, pb, psw, psb, out);
    }
}